// Round 1
// baseline (589.289 us; speedup 1.0000x reference)
//
#include <hip/hip_runtime.h>
#include <math.h>

#define BN 4096
#define DIM 256
#define D4 (DIM/4)        // 64 float4 per row
#define MI 8              // anchors per workgroup (main kernel)
#define MARGINF 0.3f
#define EPSF 1e-6f

__device__ __forceinline__ float fma4(float4 a, float4 b, float c){
  return fmaf(a.x,b.x, fmaf(a.y,b.y, fmaf(a.z,b.z, fmaf(a.w,b.w, c))));
}

// ---------------- kernel 0: per-row squared norms ----------------
__global__ __launch_bounds__(256) void k_sq(const float* __restrict__ E, float* __restrict__ sq){
  int i = blockIdx.x*256 + threadIdx.x;
  if (i >= BN) return;
  const float4* r = (const float4*)E + (size_t)i*D4;
  float a0=0.f,a1=0.f,a2=0.f,a3=0.f;
  #pragma unroll
  for (int q=0;q<D4;q+=4){
    a0 = fma4(r[q],r[q],a0);   a1 = fma4(r[q+1],r[q+1],a1);
    a2 = fma4(r[q+2],r[q+2],a2); a3 = fma4(r[q+3],r[q+3],a3);
  }
  sq[i] = (a0+a1)+(a2+a3);
}

// ------ kernel 1: per-class hardest positive (ap_dist, hp_idx, any_pos) ------
// grid = 256 blocks: 4 splits per class, class = blockIdx>>2
__global__ __launch_bounds__(256) void k_pos(const float* __restrict__ E, const int* __restrict__ labels,
                       const float* __restrict__ sq, float* __restrict__ apw,
                       int* __restrict__ hpw, int* __restrict__ anypw){
  __shared__ int labs[BN];
  __shared__ int members[1024];
  __shared__ int cntS;
  __shared__ int woff[4];
  __shared__ float4 eI[D4];
  __shared__ float redv[4]; __shared__ int redj[4];
  int t = threadIdx.x, lane = t&63, w = t>>6;
  int c = blockIdx.x >> 2, split = blockIdx.x & 3;
  for (int q=t;q<BN;q+=256) labs[q]=labels[q];
  if (t==0) cntS=0;
  __syncthreads();
  // ordered (ascending j) stream compaction of class members
  for (int base=0;base<BN;base+=256){
    bool m = (labs[base+t]==c);
    unsigned long long mask = __ballot(m);
    if (lane==0) woff[w]=__popcll(mask);
    int myoff = __popcll(mask & ((1ull<<lane)-1ull));
    __syncthreads();
    int wb = cntS;
    for (int q=0;q<w;q++) wb += woff[q];
    if (m && (wb+myoff) < 1024) members[wb+myoff] = base+t;
    __syncthreads();
    if (t==0) cntS += woff[0]+woff[1]+woff[2]+woff[3];
    __syncthreads();
  }
  int cnt = cntS; if (cnt > 1024) cnt = 1024;
  int anyp = (cnt >= 2) ? 1 : 0;
  const float4* E4 = (const float4*)E;
  for (int mi=split; mi<cnt; mi+=4){
    int i = members[mi];
    __syncthreads();                      // protect eI / redv from previous iter
    if (t < D4) eI[t] = E4[(size_t)i*D4 + t];
    __syncthreads();
    float sqi = sq[i];
    float bv = -INFINITY; int bj = 0x7fffffff;
    for (int mj=t; mj<cnt; mj+=256){
      if (mj==mi) continue;
      int j = members[mj];
      const float4* rj = E4 + (size_t)j*D4;
      float a0=0.f,a1=0.f;
      #pragma unroll
      for (int q=0;q<D4;q+=2){ a0=fma4(eI[q],rj[q],a0); a1=fma4(eI[q+1],rj[q+1],a1); }
      float d = sqrtf(fmaxf(sqi + sq[j] - 2.0f*(a0+a1), 0.0f));
      // ascending mj => ascending j; strict > keeps first occurrence of max
      if (d > bv || (d==bv && j<bj)) { bv=d; bj=j; }
    }
    #pragma unroll
    for (int off=32; off; off>>=1){
      float v2=__shfl_xor(bv,off); int j2=__shfl_xor(bj,off);
      if (v2>bv || (v2==bv && j2<bj)){ bv=v2; bj=j2; }
    }
    if (lane==0){ redv[w]=bv; redj[w]=bj; }
    __syncthreads();
    if (t==0){
      float V=-INFINITY; int J=0x7fffffff;
      for (int q=0;q<4;q++){ if (redv[q]>V || (redv[q]==V && redj[q]<J)){V=redv[q];J=redj[q];} }
      if (J==0x7fffffff) J=0;   // no positive: ref-equivalent path, anchor invalid anyway
      apw[i]=V; hpw[i]=J; anypw[i]=anyp;
    }
  }
}

// ------ kernel 2: streaming GEMM + hardest-neg / first-semi + per-anchor loss ------
// grid = 512 blocks, 8 anchors each
__global__ __launch_bounds__(256,2) void k_main(const float* __restrict__ E, const int* __restrict__ labels,
     const float* __restrict__ sq, const float* __restrict__ apw, const int* __restrict__ hpw,
     const int* __restrict__ anypw, float* __restrict__ partials){
  __shared__ int labs[BN];
  __shared__ float4 A4s[MI*D4];
  __shared__ float redv[4][MI]; __shared__ int redj[4][MI]; __shared__ int redsm[4][MI];
  __shared__ int finNeg[MI]; __shared__ int finVal[MI];
  __shared__ float redp[4], redn[4];
  int t=threadIdx.x, lane=t&63, w=t>>6;
  int a0 = blockIdx.x * MI;
  const float4* E4 = (const float4*)E;
  for (int q=t;q<BN;q+=256) labs[q]=labels[q];
  for (int q=t;q<MI*D4;q+=256) A4s[q] = E4[(size_t)a0*D4 + q];
  __syncthreads();

  float apv[MI], aphi[MI], sqi[MI]; int labi[MI];
  #pragma unroll
  for (int a=0;a<MI;a++){
    apv[a]=apw[a0+a]; aphi[a]=apv[a]+MARGINF; sqi[a]=sq[a0+a]; labi[a]=labs[a0+a];
  }
  float mnv[MI]; int mnj[MI]; int smj[MI];
  #pragma unroll
  for (int a=0;a<MI;a++){ mnv[a]=INFINITY; mnj[a]=0; smj[a]=0x7fffffff; }

  for (int g=0; g<4; g++){
    const float4* rp[4]; int jr[4];
    #pragma unroll
    for (int r=0;r<4;r++){ jr[r]=t + 256*(4*g+r); rp[r]=E4 + (size_t)jr[r]*D4; }
    float acc[MI][4];
    #pragma unroll
    for (int a=0;a<MI;a++){
      #pragma unroll
      for (int r=0;r<4;r++) acc[a][r]=0.0f;
    }
    for (int k4=0;k4<D4;k4+=4){        // 16 floats per row per step: full 64B line
      float4 b[4][4];
      #pragma unroll
      for (int r=0;r<4;r++){
        #pragma unroll
        for (int q=0;q<4;q++) b[r][q] = rp[r][k4+q];
      }
      #pragma unroll
      for (int a=0;a<MI;a++){
        #pragma unroll
        for (int q=0;q<4;q++){
          float4 af = A4s[a*D4 + k4 + q];    // wave-uniform address: LDS broadcast
          #pragma unroll
          for (int r=0;r<4;r++) acc[a][r] = fma4(af, b[r][q], acc[a][r]);
        }
      }
    }
    #pragma unroll
    for (int r=0;r<4;r++){
      int j=jr[r]; int lj=labs[j];
      float sqj = sq[j];
      #pragma unroll
      for (int a=0;a<MI;a++){
        float d = sqrtf(fmaxf(sqi[a]+sqj-2.0f*acc[a][r], 0.0f));
        if (lj != labi[a]){
          // ascending j within thread: strict < keeps first occurrence of min
          if (d < mnv[a]){ mnv[a]=d; mnj[a]=j; }
          if (d > apv[a] && d < aphi[a] && j < smj[a]) smj[a]=j;
        }
      }
    }
  }

  // cross-thread reductions (first-index tie-breaks on j)
  #pragma unroll
  for (int a=0;a<MI;a++){
    float v=mnv[a]; int j=mnj[a]; int s=smj[a];
    #pragma unroll
    for (int off=32; off; off>>=1){
      float v2=__shfl_xor(v,off); int j2=__shfl_xor(j,off); int s2=__shfl_xor(s,off);
      if (v2<v || (v2==v && j2<j)){ v=v2; j=j2; }
      s = (s2<s)?s2:s;
    }
    if (lane==0){ redv[w][a]=v; redj[w][a]=j; redsm[w][a]=s; }
  }
  __syncthreads();
  if (t < MI){
    int a=t;
    float V=INFINITY; int J=0; int S=0x7fffffff; bool first=true;
    for (int q=0;q<4;q++){
      float v2=redv[q][a]; int j2=redj[q][a];
      if (first || v2<V || (v2==V && j2<J)){ V=v2; J=j2; first=false; }
      int s2=redsm[q][a]; S=(s2<S)?s2:S;
    }
    bool anyneg = (V < INFINITY);
    finNeg[a] = (S != 0x7fffffff) ? S : J;
    finVal[a] = (anypw[a0+a] != 0 && anyneg) ? 1 : 0;
  }
  __syncthreads();

  // per-anchor triplet loss, recomputed from embeddings (+EPS inside norm)
  const float* Af = (const float*)A4s;
  float lsum=0.0f, lcnt=0.0f;
  for (int a=0;a<MI;a++){
    if (finVal[a]){                       // uniform branch (LDS value)
      int hp = hpw[a0+a]; int ng = finNeg[a];
      float ai = Af[a*DIM + t];
      float pv = E[(size_t)hp*DIM + t];
      float nv = E[(size_t)ng*DIM + t];
      float dp = ai - pv + EPSF; float dn = ai - nv + EPSF;
      float sp = dp*dp, sn = dn*dn;
      #pragma unroll
      for (int off=32; off; off>>=1){ sp += __shfl_xor(sp,off); sn += __shfl_xor(sn,off); }
      if (lane==0){ redp[w]=sp; redn[w]=sn; }
    }
    __syncthreads();
    if (finVal[a] && t==0){
      float SP=(redp[0]+redp[1])+(redp[2]+redp[3]);
      float SN=(redn[0]+redn[1])+(redn[2]+redn[3]);
      lsum += fmaxf(sqrtf(SP)-sqrtf(SN)+MARGINF, 0.0f);
      lcnt += 1.0f;
    }
    __syncthreads();
  }
  if (t==0){ partials[2*blockIdx.x]=lsum; partials[2*blockIdx.x+1]=lcnt; }
}

// ---------------- kernel 3: final deterministic reduce ----------------
__global__ __launch_bounds__(256) void k_fin(const float* __restrict__ partials, float* __restrict__ out){
  __shared__ float rs[4], rc[4];
  int t=threadIdx.x, lane=t&63, w=t>>6;
  float s=0.f, c=0.f;
  for (int q=t;q<512;q+=256){ s+=partials[2*q]; c+=partials[2*q+1]; }
  #pragma unroll
  for (int off=32; off; off>>=1){ s+=__shfl_xor(s,off); c+=__shfl_xor(c,off); }
  if (lane==0){ rs[w]=s; rc[w]=c; }
  __syncthreads();
  if (t==0){
    float S=(rs[0]+rs[1])+(rs[2]+rs[3]);
    float C=(rc[0]+rc[1])+(rc[2]+rc[3]);
    out[0] = (C>0.0f) ? S/fmaxf(C,1.0f) : 0.0f;
  }
}

extern "C" void kernel_launch(void* const* d_in, const int* in_sizes, int n_in,
                              void* d_out, int out_size, void* d_ws, size_t ws_size,
                              hipStream_t stream) {
  const float* E      = (const float*)d_in[0];   // 4096x256 fp32
  const int*   labels = (const int*)d_in[1];     // 4096 int32
  float* out = (float*)d_out;

  // workspace layout (all fp32/int32, ~70 KB total)
  float* sqw      = (float*)d_ws;          // 4096
  float* apw      = sqw + BN;              // 4096
  int*   hpw      = (int*)(apw + BN);      // 4096
  int*   anypw    = hpw + BN;              // 4096
  float* partials = (float*)(anypw + BN);  // 1024

  k_sq  <<<BN/256, 256, 0, stream>>>(E, sqw);
  k_pos <<<256,    256, 0, stream>>>(E, labels, sqw, apw, hpw, anypw);
  k_main<<<BN/MI,  256, 0, stream>>>(E, labels, sqw, apw, hpw, anypw, partials);
  k_fin <<<1,      256, 0, stream>>>(partials, out);
}

// Round 2
// 496.215 us; speedup vs baseline: 1.1876x; 1.1876x over previous
//
#include <hip/hip_runtime.h>
#include <math.h>

#define BN 4096
#define DIM 256
#define D4 (DIM/4)        // 64 float4 per row
#define MI 8              // anchors per workgroup (main kernel)
#define MARGINF 0.3f
#define EPSF 1e-6f
#define NCOLS 1024        // columns per group in k_main (4 per thread)
#define NCH 16            // k-chunks per group (4 quads = 16 floats each)
#define BP 1025           // padded plane stride (float4) for Bs

__device__ __forceinline__ float fma4(float4 a, float4 b, float c){
  return fmaf(a.x,b.x, fmaf(a.y,b.y, fmaf(a.z,b.z, fmaf(a.w,b.w, c))));
}

// ---------------- kernel 0: per-row squared norms ----------------
__global__ __launch_bounds__(256) void k_sq(const float* __restrict__ E, float* __restrict__ sq){
  int i = blockIdx.x*256 + threadIdx.x;
  if (i >= BN) return;
  const float4* r = (const float4*)E + (size_t)i*D4;
  float a0=0.f,a1=0.f,a2=0.f,a3=0.f;
  #pragma unroll
  for (int q=0;q<D4;q+=4){
    a0 = fma4(r[q],r[q],a0);   a1 = fma4(r[q+1],r[q+1],a1);
    a2 = fma4(r[q+2],r[q+2],a2); a3 = fma4(r[q+3],r[q+3],a3);
  }
  sq[i] = (a0+a1)+(a2+a3);
}

// ------ kernel 1: per-class hardest positive (ap_dist, hp_idx, any_pos) ------
// grid = 256 blocks: 4 splits per class, class = blockIdx>>2
// v2: 4 lanes per candidate column (lane p owns dims p+4m) -> full thread
// utilization + coalesced 64B-segment loads (16 lines/wave-inst, not 64).
__global__ __launch_bounds__(256) void k_pos(const float* __restrict__ E, const int* __restrict__ labels,
                       const float* __restrict__ sq, float* __restrict__ apw,
                       int* __restrict__ hpw, int* __restrict__ anypw){
  __shared__ int labs[BN];
  __shared__ int members[1024];
  __shared__ int cntS;
  __shared__ int woff[4];
  __shared__ float4 eI[D4];
  __shared__ float redv[4]; __shared__ int redj[4];
  int t = threadIdx.x, lane = t&63, w = t>>6;
  int c = blockIdx.x >> 2, split = blockIdx.x & 3;
  for (int q=t;q<BN;q+=256) labs[q]=labels[q];
  if (t==0) cntS=0;
  __syncthreads();
  // ordered (ascending j) stream compaction of class members
  for (int base=0;base<BN;base+=256){
    bool m = (labs[base+t]==c);
    unsigned long long mask = __ballot(m);
    if (lane==0) woff[w]=__popcll(mask);
    int myoff = __popcll(mask & ((1ull<<lane)-1ull));
    __syncthreads();
    int wb = cntS;
    for (int q=0;q<w;q++) wb += woff[q];
    if (m && (wb+myoff) < 1024) members[wb+myoff] = base+t;
    __syncthreads();
    if (t==0) cntS += woff[0]+woff[1]+woff[2]+woff[3];
    __syncthreads();
  }
  int cnt = cntS; if (cnt > 1024) cnt = 1024;
  int anyp = (cnt >= 2) ? 1 : 0;
  const float4* E4 = (const float4*)E;
  int p = t&3, mj0 = t>>2;
  int passes = (cnt+63)>>6;
  for (int mi=split; mi<cnt; mi+=4){
    int i = members[mi];
    __syncthreads();                      // protect eI / redv from previous iter
    if (t < D4) eI[t] = E4[(size_t)i*D4 + t];
    __syncthreads();
    float sqi = sq[i];
    float bv = -INFINITY; int bj = 0x7fffffff;
    for (int ps=0; ps<passes; ps++){
      int mj = mj0 + (ps<<6);
      if (mj < cnt && mj != mi){
        int j = members[mj];
        const float4* rj = E4 + (size_t)j*D4 + p;
        float a0=0.f, a1=0.f;
        #pragma unroll
        for (int m=0;m<16;m+=2){
          a0 = fma4(eI[p+4*m],     rj[4*m],     a0);
          a1 = fma4(eI[p+4*(m+1)], rj[4*(m+1)], a1);
        }
        float acc = a0+a1;
        acc += __shfl_xor(acc,1); acc += __shfl_xor(acc,2);   // 4-lane partial sum
        float d = sqrtf(fmaxf(sqi + sq[j] - 2.0f*acc, 0.0f));
        // ascending mj across passes => ascending j; strict > keeps first max
        if (p==0){ if (d > bv || (d==bv && j<bj)){ bv=d; bj=j; } }
      }
    }
    #pragma unroll
    for (int off=32; off; off>>=1){
      float v2=__shfl_xor(bv,off); int j2=__shfl_xor(bj,off);
      if (v2>bv || (v2==bv && j2<bj)){ bv=v2; bj=j2; }
    }
    if (lane==0){ redv[w]=bv; redj[w]=bj; }
    __syncthreads();
    if (t==0){
      float V=-INFINITY; int J=0x7fffffff;
      for (int q=0;q<4;q++){ if (redv[q]>V || (redv[q]==V && redj[q]<J)){V=redv[q];J=redj[q];} }
      if (J==0x7fffffff) J=0;   // no positive: anchor invalid anyway
      apw[i]=V; hpw[i]=J; anypw[i]=anyp;
    }
  }
}

// ------ kernel 2: streaming GEMM + hardest-neg / first-semi + per-anchor loss ------
// grid = 512 blocks, 8 anchors each.
// v2: B staged through LDS per 16-float k-chunk in quad-plane layout
// (plane stride BP=1025 float4 -> staggered banks), coalesced global loads.
__global__ __launch_bounds__(256,2) void k_main(const float* __restrict__ E, const int* __restrict__ labels,
     const float* __restrict__ sq, const float* __restrict__ apw, const int* __restrict__ hpw,
     const int* __restrict__ anypw, float* __restrict__ partials){
  __shared__ float4 A4s[MI*D4];         // 8 KB anchor rows
  __shared__ float4 Bs[4*BP];           // 64.06 KB staged B chunk (4 quad-planes)
  __shared__ float redv[4][MI]; __shared__ int redj[4][MI]; __shared__ int redsm[4][MI];
  __shared__ int finNeg[MI]; __shared__ int finVal[MI];
  __shared__ float redp[4], redn[4];
  int t=threadIdx.x, lane=t&63, w=t>>6;
  int a0 = blockIdx.x * MI;
  const float4* E4 = (const float4*)E;
  for (int q=t;q<MI*D4;q+=256) A4s[q] = E4[(size_t)a0*D4 + q];
  __syncthreads();

  float apv[MI], aphi[MI], sqi[MI]; int labi[MI];
  #pragma unroll
  for (int a=0;a<MI;a++){
    apv[a]=apw[a0+a]; aphi[a]=apv[a]+MARGINF; sqi[a]=sq[a0+a]; labi[a]=labels[a0+a];
  }
  float mnv[MI]; int mnj[MI]; int smj[MI];
  #pragma unroll
  for (int a=0;a<MI;a++){ mnv[a]=INFINITY; mnj[a]=0; smj[a]=0x7fffffff; }

  int sq_ = t&3, sr0 = t>>2;           // staging: lane quad + base row
  for (int g=0; g<4; g++){
    int rbase = g*NCOLS;
    float acc[MI][4];
    #pragma unroll
    for (int a=0;a<MI;a++){
      #pragma unroll
      for (int c=0;c<4;c++) acc[a][c]=0.0f;
    }
    for (int kc=0; kc<NCH; kc++){
      __syncthreads();                 // previous chunk's compute done
      // stage 1024 rows x 4 quads, two batches of 8 outstanding loads
      #pragma unroll
      for (int h=0; h<2; h++){
        float4 tmp[8];
        #pragma unroll
        for (int s=0;s<8;s++){
          int r = sr0 + 64*(8*h+s);
          tmp[s] = E4[(size_t)(rbase + r)*D4 + kc*4 + sq_];
        }
        #pragma unroll
        for (int s=0;s<8;s++){
          int r = sr0 + 64*(8*h+s);
          Bs[sq_*BP + r] = tmp[s];
        }
      }
      __syncthreads();
      // compute: 8 anchors x 4 cols x 4 quads
      #pragma unroll
      for (int q2=0;q2<4;q2++){
        float4 a_[MI];
        #pragma unroll
        for (int a=0;a<MI;a++) a_[a] = A4s[a*D4 + kc*4 + q2];  // wave-uniform broadcast
        #pragma unroll
        for (int c=0;c<4;c++){
          float4 b = Bs[q2*BP + t + 256*c];                    // lane-consecutive b128
          #pragma unroll
          for (int a=0;a<MI;a++) acc[a][c] = fma4(a_[a], b, acc[a][c]);
        }
      }
    }
    // distances & selection for this group's columns (j ascending in c)
    #pragma unroll
    for (int c=0;c<4;c++){
      int j = rbase + 256*c + t;
      int lj = labels[j];
      float sqj = sq[j];
      #pragma unroll
      for (int a=0;a<MI;a++){
        float d = sqrtf(fmaxf(sqi[a]+sqj-2.0f*acc[a][c], 0.0f));
        if (lj != labi[a]){
          if (d < mnv[a]){ mnv[a]=d; mnj[a]=j; }               // strict <: first min
          if (d > apv[a] && d < aphi[a] && j < smj[a]) smj[a]=j;
        }
      }
    }
  }

  // cross-thread reductions (first-index tie-breaks on j)
  #pragma unroll
  for (int a=0;a<MI;a++){
    float v=mnv[a]; int j=mnj[a]; int s=smj[a];
    #pragma unroll
    for (int off=32; off; off>>=1){
      float v2=__shfl_xor(v,off); int j2=__shfl_xor(j,off); int s2=__shfl_xor(s,off);
      if (v2<v || (v2==v && j2<j)){ v=v2; j=j2; }
      s = (s2<s)?s2:s;
    }
    if (lane==0){ redv[w][a]=v; redj[w][a]=j; redsm[w][a]=s; }
  }
  __syncthreads();
  if (t < MI){
    int a=t;
    float V=INFINITY; int J=0; int S=0x7fffffff; bool first=true;
    for (int q=0;q<4;q++){
      float v2=redv[q][a]; int j2=redj[q][a];
      if (first || v2<V || (v2==V && j2<J)){ V=v2; J=j2; first=false; }
      int s2=redsm[q][a]; S=(s2<S)?s2:S;
    }
    bool anyneg = (V < INFINITY);
    finNeg[a] = (S != 0x7fffffff) ? S : J;
    finVal[a] = (anypw[a0+a] != 0 && anyneg) ? 1 : 0;
  }
  __syncthreads();

  // per-anchor triplet loss, recomputed from embeddings (+EPS inside norm)
  const float* Af = (const float*)A4s;
  float lsum=0.0f, lcnt=0.0f;
  for (int a=0;a<MI;a++){
    if (finVal[a]){                       // uniform branch (LDS value)
      int hp = hpw[a0+a]; int ng = finNeg[a];
      float ai = Af[a*DIM + t];
      float pv = E[(size_t)hp*DIM + t];
      float nv = E[(size_t)ng*DIM + t];
      float dp = ai - pv + EPSF; float dn = ai - nv + EPSF;
      float sp = dp*dp, sn = dn*dn;
      #pragma unroll
      for (int off=32; off; off>>=1){ sp += __shfl_xor(sp,off); sn += __shfl_xor(sn,off); }
      if (lane==0){ redp[w]=sp; redn[w]=sn; }
    }
    __syncthreads();
    if (finVal[a] && t==0){
      float SP=(redp[0]+redp[1])+(redp[2]+redp[3]);
      float SN=(redn[0]+redn[1])+(redn[2]+redn[3]);
      lsum += fmaxf(sqrtf(SP)-sqrtf(SN)+MARGINF, 0.0f);
      lcnt += 1.0f;
    }
    __syncthreads();
  }
  if (t==0){ partials[2*blockIdx.x]=lsum; partials[2*blockIdx.x+1]=lcnt; }
}

// ---------------- kernel 3: final deterministic reduce ----------------
__global__ __launch_bounds__(256) void k_fin(const float* __restrict__ partials, float* __restrict__ out){
  __shared__ float rs[4], rc[4];
  int t=threadIdx.x, lane=t&63, w=t>>6;
  float s=0.f, c=0.f;
  for (int q=t;q<512;q+=256){ s+=partials[2*q]; c+=partials[2*q+1]; }
  #pragma unroll
  for (int off=32; off; off>>=1){ s+=__shfl_xor(s,off); c+=__shfl_xor(c,off); }
  if (lane==0){ rs[w]=s; rc[w]=c; }
  __syncthreads();
  if (t==0){
    float S=(rs[0]+rs[1])+(rs[2]+rs[3]);
    float C=(rc[0]+rc[1])+(rc[2]+rc[3]);
    out[0] = (C>0.0f) ? S/fmaxf(C,1.0f) : 0.0f;
  }
}

extern "C" void kernel_launch(void* const* d_in, const int* in_sizes, int n_in,
                              void* d_out, int out_size, void* d_ws, size_t ws_size,
                              hipStream_t stream) {
  const float* E      = (const float*)d_in[0];   // 4096x256 fp32
  const int*   labels = (const int*)d_in[1];     // 4096 int32
  float* out = (float*)d_out;

  // workspace layout (all fp32/int32, ~70 KB total)
  float* sqw      = (float*)d_ws;          // 4096
  float* apw      = sqw + BN;              // 4096
  int*   hpw      = (int*)(apw + BN);      // 4096
  int*   anypw    = hpw + BN;              // 4096
  float* partials = (float*)(anypw + BN);  // 1024

  k_sq  <<<BN/256, 256, 0, stream>>>(E, sqw);
  k_pos <<<256,    256, 0, stream>>>(E, labels, sqw, apw, hpw, anypw);
  k_main<<<BN/MI,  256, 0, stream>>>(E, labels, sqw, apw, hpw, anypw, partials);
  k_fin <<<1,      256, 0, stream>>>(partials, out);
}

// Round 3
// 327.636 us; speedup vs baseline: 1.7986x; 1.5145x over previous
//
#include <hip/hip_runtime.h>
#include <math.h>

#define BN 4096
#define DIM 256
#define D4 (DIM/4)        // 64 float4 per row
#define MI 8              // anchors per workgroup (main kernel)
#define MARGINF 0.3f
#define EPSF 1e-6f
#define SCAP 96           // staged class-member rows in k_pos (LDS)

__device__ __forceinline__ float fma4(float4 a, float4 b, float c){
  return fmaf(a.x,b.x, fmaf(a.y,b.y, fmaf(a.z,b.z, fmaf(a.w,b.w, c))));
}

// ---------------- kernel 0: per-row squared norms ----------------
__global__ __launch_bounds__(256) void k_sq(const float* __restrict__ E, float* __restrict__ sq){
  int i = blockIdx.x*256 + threadIdx.x;
  if (i >= BN) return;
  const float4* r = (const float4*)E + (size_t)i*D4;
  float a0=0.f,a1=0.f,a2=0.f,a3=0.f;
  #pragma unroll
  for (int q=0;q<D4;q+=4){
    a0 = fma4(r[q],r[q],a0);   a1 = fma4(r[q+1],r[q+1],a1);
    a2 = fma4(r[q+2],r[q+2],a2); a3 = fma4(r[q+3],r[q+3],a3);
  }
  sq[i] = (a0+a1)+(a2+a3);
}

// ------ kernel 1: per-class hardest positive (ap_dist, hp_idx, any_pos) ------
// grid = 256 blocks: 4 splits per class, class = blockIdx>>2
// v3: class members staged into LDS (row stride 65 f4 -> conflict-free);
// inner loops run from LDS, global fallback only if class > SCAP members.
__global__ __launch_bounds__(256) void k_pos(const float* __restrict__ E, const int* __restrict__ labels,
                       const float* __restrict__ sq, float* __restrict__ apw,
                       int* __restrict__ hpw, int* __restrict__ anypw){
  __shared__ int labs[BN];
  __shared__ int members[1024];
  __shared__ float4 mem4[SCAP*65];      // ~99.8 KB staged member rows
  __shared__ int cntS;
  __shared__ int woff[4];
  __shared__ float4 eI[D4];
  __shared__ float redv[4]; __shared__ int redj[4];
  int t = threadIdx.x, lane = t&63, w = t>>6;
  int c = blockIdx.x >> 2, split = blockIdx.x & 3;
  for (int q=t;q<BN;q+=256) labs[q]=labels[q];
  if (t==0) cntS=0;
  __syncthreads();
  // ordered (ascending j) stream compaction of class members
  for (int base=0;base<BN;base+=256){
    bool m = (labs[base+t]==c);
    unsigned long long mask = __ballot(m);
    if (lane==0) woff[w]=__popcll(mask);
    int myoff = __popcll(mask & ((1ull<<lane)-1ull));
    __syncthreads();
    int wb = cntS;
    for (int q=0;q<w;q++) wb += woff[q];
    if (m && (wb+myoff) < 1024) members[wb+myoff] = base+t;
    __syncthreads();
    if (t==0) cntS += woff[0]+woff[1]+woff[2]+woff[3];
    __syncthreads();
  }
  int cnt = cntS; if (cnt > 1024) cnt = 1024;
  int S = (cnt < SCAP) ? cnt : SCAP;
  int anyp = (cnt >= 2) ? 1 : 0;
  const float4* E4 = (const float4*)E;
  // stage member rows into LDS (coalesced: 64 consecutive lanes per row)
  for (int idx=t; idx<S*64; idx+=256){
    int row = idx>>6, f = idx&63;
    mem4[row*65 + f] = E4[(size_t)members[row]*D4 + f];
  }
  __syncthreads();
  int p = t&3, mj0 = t>>2;
  int passes = (cnt+63)>>6;
  for (int mi=split; mi<cnt; mi+=4){
    int i = members[mi];
    __syncthreads();                      // protect eI / redv from previous iter
    if (t < D4) eI[t] = (mi < S) ? mem4[mi*65 + t] : E4[(size_t)i*D4 + t];
    __syncthreads();
    float sqi = sq[i];
    float bv = -INFINITY; int bj = 0x7fffffff;
    for (int ps=0; ps<passes; ps++){
      int mj = mj0 + (ps<<6);
      if (mj < cnt && mj != mi){
        int j = members[mj];
        float a0=0.f, a1=0.f;
        if (mj < S){
          const float4* rj = mem4 + mj*65 + p;
          #pragma unroll
          for (int m=0;m<16;m+=2){
            a0 = fma4(eI[p+4*m],     rj[4*m],     a0);
            a1 = fma4(eI[p+4*(m+1)], rj[4*(m+1)], a1);
          }
        } else {
          const float4* rj = E4 + (size_t)j*D4 + p;
          #pragma unroll
          for (int m=0;m<16;m+=2){
            a0 = fma4(eI[p+4*m],     rj[4*m],     a0);
            a1 = fma4(eI[p+4*(m+1)], rj[4*(m+1)], a1);
          }
        }
        float acc = a0+a1;
        acc += __shfl_xor(acc,1); acc += __shfl_xor(acc,2);   // 4-lane partial sum
        float d = sqrtf(fmaxf(sqi + sq[j] - 2.0f*acc, 0.0f));
        // ascending mj across passes => ascending j; strict > keeps first max
        if (p==0){ if (d > bv || (d==bv && j<bj)){ bv=d; bj=j; } }
      }
    }
    #pragma unroll
    for (int off=32; off; off>>=1){
      float v2=__shfl_xor(bv,off); int j2=__shfl_xor(bj,off);
      if (v2>bv || (v2==bv && j2<bj)){ bv=v2; bj=j2; }
    }
    if (lane==0){ redv[w]=bv; redj[w]=bj; }
    __syncthreads();
    if (t==0){
      float V=-INFINITY; int J=0x7fffffff;
      for (int q=0;q<4;q++){ if (redv[q]>V || (redv[q]==V && redj[q]<J)){V=redv[q];J=redj[q];} }
      if (J==0x7fffffff) J=0;   // no positive: anchor invalid anyway
      apw[i]=V; hpw[i]=J; anypw[i]=anyp;
    }
  }
}

// ------ kernel 2: streaming GEMM + hardest-neg / first-semi + per-anchor loss ------
// v3: NO LDS staging for B (the LDS pipe was the bound). 4-lane-per-column
// k-split: thread (s=t>>2, p=t&3) owns cols colb+4s+c and quad-slice p+4m.
// B loads are full-64B-line coalesced, single-touch, straight from L1/L2.
// Only A lives in LDS, permuted At[a][p][m] (stride-17 pad -> conflict-free
// 4-way multicast reads). Partial dots merged by xor-butterfly over the quad.
__global__ __launch_bounds__(256,2) void k_main(const float* __restrict__ E, const int* __restrict__ labels,
     const float* __restrict__ sq, const float* __restrict__ apw, const int* __restrict__ hpw,
     const int* __restrict__ anypw, float* __restrict__ partials){
  __shared__ float4 At[MI*68 + 4];      // a*68 + p*17 + m   (8.7 KB)
  __shared__ float redv[4][MI]; __shared__ int redj[4][MI]; __shared__ int redsm[4][MI];
  __shared__ int finNeg[MI]; __shared__ int finVal[MI];
  __shared__ float redp[4], redn[4];
  int t=threadIdx.x, lane=t&63, w=t>>6;
  int a0 = blockIdx.x * MI;
  const float4* E4 = (const float4*)E;
  // permuted A-tile: quad q = p + 4m  ->  At[a*68 + p*17 + m]
  for (int idx=t; idx<MI*64; idx+=256){
    int a=idx>>6, q=idx&63, pp=q&3, mm=q>>2;
    At[a*68 + pp*17 + mm] = E4[(size_t)(a0+a)*D4 + q];
  }
  __syncthreads();

  float apv[MI], sqi[MI]; int labi[MI];
  #pragma unroll
  for (int a=0;a<MI;a++){
    apv[a]=apw[a0+a]; sqi[a]=sq[a0+a]; labi[a]=labels[a0+a];
  }
  float mnv[MI]; int mnj[MI]; int smj[MI];
  #pragma unroll
  for (int a=0;a<MI;a++){ mnv[a]=INFINITY; mnj[a]=0; smj[a]=0x7fffffff; }

  int s = t>>2, p = t&3;
  for (int it=0; it<16; it++){
    int colb = it*256 + 4*s;                      // this thread's first col
    const float4* __restrict__ bp = E4 + (size_t)colb*D4 + p;
    float acc[MI][4];
    #pragma unroll
    for (int a=0;a<MI;a++){
      #pragma unroll
      for (int c2=0;c2<4;c2++) acc[a][c2]=0.0f;
    }
    for (int mg=0; mg<4; mg++){
      float4 b[4][4];                             // [m][c]
      #pragma unroll
      for (int c2=0;c2<4;c2++){
        #pragma unroll
        for (int m=0;m<4;m++)
          b[m][c2] = bp[(size_t)c2*D4 + mg*16 + m*4];   // full 64B line per (c,mg) across 4 p-lanes
      }
      #pragma unroll
      for (int a=0;a<MI;a++){
        float4 a4[4];
        #pragma unroll
        for (int m=0;m<4;m++) a4[m] = At[a*68 + p*17 + mg*4 + m];
        #pragma unroll
        for (int m=0;m<4;m++){
          #pragma unroll
          for (int c2=0;c2<4;c2++) acc[a][c2] = fma4(a4[m], b[m][c2], acc[a][c2]);
        }
      }
    }
    // merge quad partial sums (bit-identical across the 4 p-lanes)
    #pragma unroll
    for (int a=0;a<MI;a++){
      #pragma unroll
      for (int c2=0;c2<4;c2++){
        float v = acc[a][c2];
        v += __shfl_xor(v,1); v += __shfl_xor(v,2);
        acc[a][c2] = v;
      }
    }
    // selection epilogue: 4 cols per thread, j ascending
    #pragma unroll
    for (int c2=0;c2<4;c2++){
      int j = colb + c2;
      int lj = labels[j]; float sqj = sq[j];
      #pragma unroll
      for (int a=0;a<MI;a++){
        float d = sqrtf(fmaxf(sqi[a]+sqj-2.0f*acc[a][c2], 0.0f));
        if (lj != labi[a]){
          if (d < mnv[a]){ mnv[a]=d; mnj[a]=j; }            // strict <: first min
          if (d > apv[a] && d < apv[a]+MARGINF && j < smj[a]) smj[a]=j;
        }
      }
    }
  }

  // cross-thread reductions (first-index tie-breaks on j)
  #pragma unroll
  for (int a=0;a<MI;a++){
    float v=mnv[a]; int j=mnj[a]; int sm=smj[a];
    #pragma unroll
    for (int off=32; off; off>>=1){
      float v2=__shfl_xor(v,off); int j2=__shfl_xor(j,off); int s2=__shfl_xor(sm,off);
      if (v2<v || (v2==v && j2<j)){ v=v2; j=j2; }
      sm = (s2<sm)?s2:sm;
    }
    if (lane==0){ redv[w][a]=v; redj[w][a]=j; redsm[w][a]=sm; }
  }
  __syncthreads();
  if (t < MI){
    int a=t;
    float V=INFINITY; int J=0; int S=0x7fffffff; bool first=true;
    for (int q=0;q<4;q++){
      float v2=redv[q][a]; int j2=redj[q][a];
      if (first || v2<V || (v2==V && j2<J)){ V=v2; J=j2; first=false; }
      int s2=redsm[q][a]; S=(s2<S)?s2:S;
    }
    bool anyneg = (V < INFINITY);
    finNeg[a] = (S != 0x7fffffff) ? S : J;
    finVal[a] = (anypw[a0+a] != 0 && anyneg) ? 1 : 0;
  }
  __syncthreads();

  // per-anchor triplet loss, recomputed from embeddings (+EPS inside norm)
  float lsum=0.0f, lcnt=0.0f;
  for (int a=0;a<MI;a++){
    if (finVal[a]){                       // uniform branch (LDS value)
      int hp = hpw[a0+a]; int ng = finNeg[a];
      float ai = E[(size_t)(a0+a)*DIM + t];
      float pv = E[(size_t)hp*DIM + t];
      float nv = E[(size_t)ng*DIM + t];
      float dp = ai - pv + EPSF; float dn = ai - nv + EPSF;
      float sp = dp*dp, sn = dn*dn;
      #pragma unroll
      for (int off=32; off; off>>=1){ sp += __shfl_xor(sp,off); sn += __shfl_xor(sn,off); }
      if (lane==0){ redp[w]=sp; redn[w]=sn; }
    }
    __syncthreads();
    if (finVal[a] && t==0){
      float SP=(redp[0]+redp[1])+(redp[2]+redp[3]);
      float SN=(redn[0]+redn[1])+(redn[2]+redn[3]);
      lsum += fmaxf(sqrtf(SP)-sqrtf(SN)+MARGINF, 0.0f);
      lcnt += 1.0f;
    }
    __syncthreads();
  }
  if (t==0){ partials[2*blockIdx.x]=lsum; partials[2*blockIdx.x+1]=lcnt; }
}

// ---------------- kernel 3: final deterministic reduce ----------------
__global__ __launch_bounds__(256) void k_fin(const float* __restrict__ partials, float* __restrict__ out){
  __shared__ float rs[4], rc[4];
  int t=threadIdx.x, lane=t&63, w=t>>6;
  float s=0.f, c=0.f;
  for (int q=t;q<512;q+=256){ s+=partials[2*q]; c+=partials[2*q+1]; }
  #pragma unroll
  for (int off=32; off; off>>=1){ s+=__shfl_xor(s,off); c+=__shfl_xor(c,off); }
  if (lane==0){ rs[w]=s; rc[w]=c; }
  __syncthreads();
  if (t==0){
    float S=(rs[0]+rs[1])+(rs[2]+rs[3]);
    float C=(rc[0]+rc[1])+(rc[2]+rc[3]);
    out[0] = (C>0.0f) ? S/fmaxf(C,1.0f) : 0.0f;
  }
}

extern "C" void kernel_launch(void* const* d_in, const int* in_sizes, int n_in,
                              void* d_out, int out_size, void* d_ws, size_t ws_size,
                              hipStream_t stream) {
  const float* E      = (const float*)d_in[0];   // 4096x256 fp32
  const int*   labels = (const int*)d_in[1];     // 4096 int32
  float* out = (float*)d_out;

  // workspace layout (all fp32/int32, ~70 KB total)
  float* sqw      = (float*)d_ws;          // 4096
  float* apw      = sqw + BN;              // 4096
  int*   hpw      = (int*)(apw + BN);      // 4096
  int*   anypw    = hpw + BN;              // 4096
  float* partials = (float*)(anypw + BN);  // 1024

  k_sq  <<<BN/256, 256, 0, stream>>>(E, sqw);
  k_pos <<<256,    256, 0, stream>>>(E, labels, sqw, apw, hpw, anypw);
  k_main<<<BN/MI,  256, 0, stream>>>(E, labels, sqw, apw, hpw, anypw, partials);
  k_fin <<<1,      256, 0, stream>>>(partials, out);
}

// Round 4
// 239.550 us; speedup vs baseline: 2.4600x; 1.3677x over previous
//
#include <hip/hip_runtime.h>
#include <math.h>

#define BN 4096
#define DIM 256
#define D4 (DIM/4)        // 64 float4 per row
#define MI 8              // anchors per workgroup (fallback k_main)
#define MT 16             // anchors per workgroup (transpose-path k_main_t)
#define MARGINF 0.3f
#define EPSF 1e-6f
#define SCAP 96           // staged class-member rows in k_pos (LDS)

typedef float v2f __attribute__((ext_vector_type(2)));

__device__ __forceinline__ float fma4(float4 a, float4 b, float c){
  return fmaf(a.x,b.x, fmaf(a.y,b.y, fmaf(a.z,b.z, fmaf(a.w,b.w, c))));
}

// ---------------- kernel 0: per-row squared norms ----------------
__global__ __launch_bounds__(256) void k_sq(const float* __restrict__ E, float* __restrict__ sq){
  int i = blockIdx.x*256 + threadIdx.x;
  if (i >= BN) return;
  const float4* r = (const float4*)E + (size_t)i*D4;
  float a0=0.f,a1=0.f,a2=0.f,a3=0.f;
  #pragma unroll
  for (int q=0;q<D4;q+=4){
    a0 = fma4(r[q],r[q],a0);   a1 = fma4(r[q+1],r[q+1],a1);
    a2 = fma4(r[q+2],r[q+2],a2); a3 = fma4(r[q+3],r[q+3],a3);
  }
  sq[i] = (a0+a1)+(a2+a3);
}

// ---------------- kernel 0b: transpose E (4096x256) -> ET (256x4096) ----------------
__global__ __launch_bounds__(256) void k_tr(const float* __restrict__ E, float* __restrict__ ET){
  __shared__ float tile[64][65];
  int t = threadIdx.x;
  int jt = blockIdx.x & 63, kt = blockIdx.x >> 6;   // 64 j-tiles x 4 k-tiles
  int j0 = jt<<6, k0 = kt<<6;
  const float4* E4 = (const float4*)E;
  int rr = t>>4, cc = t&15;
  #pragma unroll
  for (int ps=0; ps<4; ps++){
    int r = rr + ps*16;
    float4 v = E4[(size_t)(j0+r)*D4 + (k0>>2) + cc];
    tile[r][cc*4+0]=v.x; tile[r][cc*4+1]=v.y; tile[r][cc*4+2]=v.z; tile[r][cc*4+3]=v.w;
  }
  __syncthreads();
  float4* ET4 = (float4*)ET;
  #pragma unroll
  for (int ps=0; ps<4; ps++){
    int kk = rr + ps*16;
    float4 v;
    v.x = tile[cc*4+0][kk]; v.y = tile[cc*4+1][kk];
    v.z = tile[cc*4+2][kk]; v.w = tile[cc*4+3][kk];
    ET4[(size_t)(k0+kk)*1024 + (j0>>2) + cc] = v;
  }
}

// ------ kernel 1: per-class hardest positive (ap_dist, hp_idx, any_pos) ------
// v4: 4 barriers total. 2-phase count/place compaction; per-wave-independent
// mi loop (no cross-wave reduction, no barriers inside).
__global__ __launch_bounds__(256) void k_pos(const float* __restrict__ E, const int* __restrict__ labels,
                       const float* __restrict__ sq, float* __restrict__ apw,
                       int* __restrict__ hpw, int* __restrict__ anypw){
  __shared__ int members[1024];
  __shared__ float4 mem4[SCAP*65];      // ~99.8 KB staged member rows
  __shared__ int cnts[16][4];
  __shared__ int offs[16][4];
  __shared__ int cntS;
  int t = threadIdx.x, lane = t&63, w = t>>6;
  int c = blockIdx.x >> 2, split = blockIdx.x & 3;
  // phase A: per-(chunk,wave) match counts
  for (int ch=0; ch<16; ch++){
    bool m = (labels[ch*256 + t] == c);
    unsigned long long mask = __ballot(m);
    if (lane==0) cnts[ch][w] = __popcll(mask);
  }
  __syncthreads();
  if (t==0){
    int run=0;
    for (int ch=0; ch<16; ch++)
      for (int q=0;q<4;q++){ offs[ch][q]=run; run+=cnts[ch][q]; }
    cntS = run;
  }
  __syncthreads();
  int cnt = cntS; if (cnt>1024) cnt=1024;
  // phase B: ordered placement (idx ascending globally)
  for (int ch=0; ch<16; ch++){
    int idx = ch*256 + t;
    bool m = (labels[idx] == c);
    unsigned long long mask = __ballot(m);
    int my = __popcll(mask & ((1ull<<lane)-1ull));
    int pos = offs[ch][w] + my;
    if (m && pos < 1024) members[pos] = idx;
  }
  int S = (cnt < SCAP) ? cnt : SCAP;
  int anyp = (cnt >= 2) ? 1 : 0;
  __syncthreads();
  const float4* E4 = (const float4*)E;
  for (int idx=t; idx<S*64; idx+=256){
    int row = idx>>6, f = idx&63;
    mem4[row*65 + f] = E4[(size_t)members[row]*D4 + f];
  }
  __syncthreads();
  // per-wave independent mi loop; lanes: p = k-split quad, cand = candidate
  int esplit = split*4 + w;             // 0..15
  int p = lane&3, cand = lane>>2;
  int passes = (cnt+15)>>4;
  for (int mi=esplit; mi<cnt; mi+=16){
    int i = members[mi];
    float sqi = sq[i];
    // anchor k-slice into registers (dims p+4m)
    float4 ai4[16];
    if (mi < S){
      #pragma unroll
      for (int m=0;m<16;m++) ai4[m] = mem4[mi*65 + p + 4*m];
    } else {
      #pragma unroll
      for (int m=0;m<16;m++) ai4[m] = E4[(size_t)i*D4 + p + 4*m];
    }
    float bv = -INFINITY; int bj = 0x7fffffff;
    for (int ps=0; ps<passes; ps++){
      int mj = ps*16 + cand;
      if (mj < cnt && mj != mi){
        int j = members[mj];
        float a0v=0.f, a1v=0.f;
        if (mj < S){
          const float4* rj = mem4 + mj*65 + p;
          #pragma unroll
          for (int m=0;m<16;m+=2){ a0v=fma4(ai4[m],rj[4*m],a0v); a1v=fma4(ai4[m+1],rj[4*(m+1)],a1v); }
        } else {
          const float4* rj = E4 + (size_t)j*D4 + p;
          #pragma unroll
          for (int m=0;m<16;m+=2){ a0v=fma4(ai4[m],rj[4*m],a0v); a1v=fma4(ai4[m+1],rj[4*(m+1)],a1v); }
        }
        float acc = a0v+a1v;
        acc += __shfl_xor(acc,1); acc += __shfl_xor(acc,2);   // quad partial sum
        float d = sqrtf(fmaxf(sqi + sq[j] - 2.0f*acc, 0.0f));
        // ascending mj across passes => ascending j; strict > keeps first max
        if (p==0){ if (d > bv || (d==bv && j<bj)){ bv=d; bj=j; } }
      }
    }
    #pragma unroll
    for (int off=32; off; off>>=1){
      float v2=__shfl_xor(bv,off); int j2=__shfl_xor(bj,off);
      if (v2>bv || (v2==bv && j2<bj)){ bv=v2; bj=j2; }
    }
    if (lane==0){
      int J = (bj==0x7fffffff) ? 0 : bj;
      apw[i]=bv; hpw[i]=J; anypw[i]=anyp;
    }
  }
}

// ------ kernel 2 (transpose path): full-dot-per-lane GEMM + mining + loss ------
// grid = 256 blocks x 512 threads, 16 anchors each. Lane owns 4 consecutive
// cols; B from ET (coalesced); A via wave-uniform broadcast loads; packed
// v_pk_fma_f32; no LDS / no shuffles in the k-loop.
__global__ __launch_bounds__(512,2) void k_main_t(const float* __restrict__ E, const float* __restrict__ ET,
     const int* __restrict__ labels, const float* __restrict__ sq, const float* __restrict__ apw,
     const int* __restrict__ hpw, const int* __restrict__ anypw, float* __restrict__ partials){
  __shared__ float redv[8][MT]; __shared__ int redj[8][MT]; __shared__ int redsm[8][MT];
  __shared__ int finNeg[MT]; __shared__ int finVal[MT];
  __shared__ float redp[4], redn[4];
  int t=threadIdx.x, l=t&63, w=t>>6;
  int a0 = blockIdx.x * MT;
  const float4* E4  = (const float4*)E;
  const float4* ET4 = (const float4*)ET;

  float mnv[MT]; int mnj[MT]; int smj[MT];
  #pragma unroll
  for (int a=0;a<MT;a++){ mnv[a]=INFINITY; mnj[a]=0; smj[a]=0x7fffffff; }

  for (int g=0; g<2; g++){
    int it = w + 8*g;                    // this wave's column group
    int colb = it*256 + 4*l;             // lane's 4 consecutive cols
    v2f acc[MT][2];
    #pragma unroll
    for (int a=0;a<MT;a++){ acc[a][0]=(v2f)(0.0f); acc[a][1]=(v2f)(0.0f); }
    const float4* bp = ET4 + it*64 + l;  // + k*1024
    for (int kb=0; kb<64; kb++){         // 4 dims per kb
      float4 b0 = bp[(4*kb+0)*1024];
      float4 b1 = bp[(4*kb+1)*1024];
      float4 b2 = bp[(4*kb+2)*1024];
      float4 b3 = bp[(4*kb+3)*1024];
      v2f b0l={b0.x,b0.y}, b0h={b0.z,b0.w};
      v2f b1l={b1.x,b1.y}, b1h={b1.z,b1.w};
      v2f b2l={b2.x,b2.y}, b2h={b2.z,b2.w};
      v2f b3l={b3.x,b3.y}, b3h={b3.z,b3.w};
      #pragma unroll
      for (int half=0; half<2; half++){
        float4 af[8];
        #pragma unroll
        for (int a8=0;a8<8;a8++)         // wave-uniform address -> broadcast/s_load
          af[a8] = E4[(a0 + half*8 + a8)*D4 + kb];
        #pragma unroll
        for (int a8=0;a8<8;a8++){
          int a = half*8 + a8;
          v2f s;
          s = (v2f){af[a8].x, af[a8].x};
          acc[a][0] = __builtin_elementwise_fma(s, b0l, acc[a][0]);
          acc[a][1] = __builtin_elementwise_fma(s, b0h, acc[a][1]);
          s = (v2f){af[a8].y, af[a8].y};
          acc[a][0] = __builtin_elementwise_fma(s, b1l, acc[a][0]);
          acc[a][1] = __builtin_elementwise_fma(s, b1h, acc[a][1]);
          s = (v2f){af[a8].z, af[a8].z};
          acc[a][0] = __builtin_elementwise_fma(s, b2l, acc[a][0]);
          acc[a][1] = __builtin_elementwise_fma(s, b2h, acc[a][1]);
          s = (v2f){af[a8].w, af[a8].w};
          acc[a][0] = __builtin_elementwise_fma(s, b3l, acc[a][0]);
          acc[a][1] = __builtin_elementwise_fma(s, b3h, acc[a][1]);
        }
      }
    }
    // selection epilogue: 4 cols per lane, j ascending (within lane and across g)
    int4   lj4 = *(const int4*  )(labels + colb);
    float4 sj4 = *(const float4*)(sq + colb);
    float sjv[4] = {sj4.x,sj4.y,sj4.z,sj4.w};
    int   ljv[4] = {lj4.x,lj4.y,lj4.z,lj4.w};
    #pragma unroll
    for (int a=0;a<MT;a++){
      float sqa = sq[a0+a]; float apv = apw[a0+a]; int labi = labels[a0+a];
      float dot[4] = {acc[a][0].x, acc[a][0].y, acc[a][1].x, acc[a][1].y};
      #pragma unroll
      for (int c2=0;c2<4;c2++){
        int j = colb + c2;
        float d = sqrtf(fmaxf(sqa + sjv[c2] - 2.0f*dot[c2], 0.0f));
        if (ljv[c2] != labi){
          if (d < mnv[a]){ mnv[a]=d; mnj[a]=j; }             // strict <: first min
          if (d > apv && d < apv+MARGINF && j < smj[a]) smj[a]=j;
        }
      }
    }
  }

  // wave reduction then 8-wave LDS reduction (first-index tie-breaks on j)
  #pragma unroll
  for (int a=0;a<MT;a++){
    float v=mnv[a]; int j=mnj[a]; int sm=smj[a];
    #pragma unroll
    for (int off=32; off; off>>=1){
      float v2=__shfl_xor(v,off); int j2=__shfl_xor(j,off); int s2=__shfl_xor(sm,off);
      if (v2<v || (v2==v && j2<j)){ v=v2; j=j2; }
      sm = (s2<sm)?s2:sm;
    }
    if (l==0){ redv[w][a]=v; redj[w][a]=j; redsm[w][a]=sm; }
  }
  __syncthreads();
  if (t < MT){
    int a=t;
    float V=INFINITY; int J=0; int S=0x7fffffff; bool first=true;
    for (int q=0;q<8;q++){
      float v2=redv[q][a]; int j2=redj[q][a];
      if (first || v2<V || (v2==V && j2<J)){ V=v2; J=j2; first=false; }
      int s2=redsm[q][a]; S=(s2<S)?s2:S;
    }
    bool anyneg = (V < INFINITY);
    finNeg[a] = (S != 0x7fffffff) ? S : J;
    finVal[a] = (anypw[a0+a] != 0 && anyneg) ? 1 : 0;
  }
  __syncthreads();

  // per-anchor triplet loss recomputed from embeddings (+EPS inside norm)
  float lsum=0.0f, lcnt=0.0f;
  for (int a=0;a<MT;a++){
    if (t<256 && finVal[a]){            // dims handled by first 4 waves
      int hp = hpw[a0+a]; int ng = finNeg[a];
      float ai = E[(size_t)(a0+a)*DIM + t];
      float pv = E[(size_t)hp*DIM + t];
      float nv = E[(size_t)ng*DIM + t];
      float dp = ai - pv + EPSF; float dn = ai - nv + EPSF;
      float sp = dp*dp, sn = dn*dn;
      #pragma unroll
      for (int off=32; off; off>>=1){ sp += __shfl_xor(sp,off); sn += __shfl_xor(sn,off); }
      if (l==0){ redp[w]=sp; redn[w]=sn; }
    }
    __syncthreads();
    if (t==0 && finVal[a]){
      float SP=(redp[0]+redp[1])+(redp[2]+redp[3]);
      float SN=(redn[0]+redn[1])+(redn[2]+redn[3]);
      lsum += fmaxf(sqrtf(SP)-sqrtf(SN)+MARGINF, 0.0f);
      lcnt += 1.0f;
    }
    __syncthreads();
  }
  if (t==0){ partials[2*blockIdx.x]=lsum; partials[2*blockIdx.x+1]=lcnt; }
}

// ------ kernel 2 (fallback, no-transpose): round-3 k_main verbatim ------
__global__ __launch_bounds__(256,2) void k_main(const float* __restrict__ E, const int* __restrict__ labels,
     const float* __restrict__ sq, const float* __restrict__ apw, const int* __restrict__ hpw,
     const int* __restrict__ anypw, float* __restrict__ partials){
  __shared__ float4 At[MI*68 + 4];
  __shared__ float redv[4][MI]; __shared__ int redj[4][MI]; __shared__ int redsm[4][MI];
  __shared__ int finNeg[MI]; __shared__ int finVal[MI];
  __shared__ float redp[4], redn[4];
  int t=threadIdx.x, lane=t&63, w=t>>6;
  int a0 = blockIdx.x * MI;
  const float4* E4 = (const float4*)E;
  for (int idx=t; idx<MI*64; idx+=256){
    int a=idx>>6, q=idx&63, pp=q&3, mm=q>>2;
    At[a*68 + pp*17 + mm] = E4[(size_t)(a0+a)*D4 + q];
  }
  __syncthreads();
  float apv[MI], sqi[MI]; int labi[MI];
  #pragma unroll
  for (int a=0;a<MI;a++){ apv[a]=apw[a0+a]; sqi[a]=sq[a0+a]; labi[a]=labels[a0+a]; }
  float mnv[MI]; int mnj[MI]; int smj[MI];
  #pragma unroll
  for (int a=0;a<MI;a++){ mnv[a]=INFINITY; mnj[a]=0; smj[a]=0x7fffffff; }
  int s = t>>2, p = t&3;
  for (int it=0; it<16; it++){
    int colb = it*256 + 4*s;
    const float4* __restrict__ bp = E4 + (size_t)colb*D4 + p;
    float acc[MI][4];
    #pragma unroll
    for (int a=0;a<MI;a++){
      #pragma unroll
      for (int c2=0;c2<4;c2++) acc[a][c2]=0.0f;
    }
    for (int mg=0; mg<4; mg++){
      float4 b[4][4];
      #pragma unroll
      for (int c2=0;c2<4;c2++){
        #pragma unroll
        for (int m=0;m<4;m++) b[m][c2] = bp[(size_t)c2*D4 + mg*16 + m*4];
      }
      #pragma unroll
      for (int a=0;a<MI;a++){
        float4 a4[4];
        #pragma unroll
        for (int m=0;m<4;m++) a4[m] = At[a*68 + p*17 + mg*4 + m];
        #pragma unroll
        for (int m=0;m<4;m++){
          #pragma unroll
          for (int c2=0;c2<4;c2++) acc[a][c2] = fma4(a4[m], b[m][c2], acc[a][c2]);
        }
      }
    }
    #pragma unroll
    for (int a=0;a<MI;a++){
      #pragma unroll
      for (int c2=0;c2<4;c2++){
        float v = acc[a][c2];
        v += __shfl_xor(v,1); v += __shfl_xor(v,2);
        acc[a][c2] = v;
      }
    }
    #pragma unroll
    for (int c2=0;c2<4;c2++){
      int j = colb + c2;
      int lj = labels[j]; float sqj = sq[j];
      #pragma unroll
      for (int a=0;a<MI;a++){
        float d = sqrtf(fmaxf(sqi[a]+sqj-2.0f*acc[a][c2], 0.0f));
        if (lj != labi[a]){
          if (d < mnv[a]){ mnv[a]=d; mnj[a]=j; }
          if (d > apv[a] && d < apv[a]+MARGINF && j < smj[a]) smj[a]=j;
        }
      }
    }
  }
  #pragma unroll
  for (int a=0;a<MI;a++){
    float v=mnv[a]; int j=mnj[a]; int sm=smj[a];
    #pragma unroll
    for (int off=32; off; off>>=1){
      float v2=__shfl_xor(v,off); int j2=__shfl_xor(j,off); int s2=__shfl_xor(sm,off);
      if (v2<v || (v2==v && j2<j)){ v=v2; j=j2; }
      sm = (s2<sm)?s2:sm;
    }
    if (lane==0){ redv[w][a]=v; redj[w][a]=j; redsm[w][a]=sm; }
  }
  __syncthreads();
  if (t < MI){
    int a=t;
    float V=INFINITY; int J=0; int S=0x7fffffff; bool first=true;
    for (int q=0;q<4;q++){
      float v2=redv[q][a]; int j2=redj[q][a];
      if (first || v2<V || (v2==V && j2<J)){ V=v2; J=j2; first=false; }
      int s2=redsm[q][a]; S=(s2<S)?s2:S;
    }
    bool anyneg = (V < INFINITY);
    finNeg[a] = (S != 0x7fffffff) ? S : J;
    finVal[a] = (anypw[a0+a] != 0 && anyneg) ? 1 : 0;
  }
  __syncthreads();
  float lsum=0.0f, lcnt=0.0f;
  for (int a=0;a<MI;a++){
    if (finVal[a]){
      int hp = hpw[a0+a]; int ng = finNeg[a];
      float ai = E[(size_t)(a0+a)*DIM + t];
      float pv = E[(size_t)hp*DIM + t];
      float nv = E[(size_t)ng*DIM + t];
      float dp = ai - pv + EPSF; float dn = ai - nv + EPSF;
      float sp = dp*dp, sn = dn*dn;
      #pragma unroll
      for (int off=32; off; off>>=1){ sp += __shfl_xor(sp,off); sn += __shfl_xor(sn,off); }
      if (lane==0){ redp[w]=sp; redn[w]=sn; }
    }
    __syncthreads();
    if (finVal[a] && t==0){
      float SP=(redp[0]+redp[1])+(redp[2]+redp[3]);
      float SN=(redn[0]+redn[1])+(redn[2]+redn[3]);
      lsum += fmaxf(sqrtf(SP)-sqrtf(SN)+MARGINF, 0.0f);
      lcnt += 1.0f;
    }
    __syncthreads();
  }
  if (t==0){ partials[2*blockIdx.x]=lsum; partials[2*blockIdx.x+1]=lcnt; }
}

// ---------------- kernel 3: final deterministic reduce ----------------
__global__ __launch_bounds__(256) void k_fin(const float* __restrict__ partials, float* __restrict__ out, int nb){
  __shared__ float rs[4], rc[4];
  int t=threadIdx.x, lane=t&63, w=t>>6;
  float s=0.f, c=0.f;
  for (int q=t;q<nb;q+=256){ s+=partials[2*q]; c+=partials[2*q+1]; }
  #pragma unroll
  for (int off=32; off; off>>=1){ s+=__shfl_xor(s,off); c+=__shfl_xor(c,off); }
  if (lane==0){ rs[w]=s; rc[w]=c; }
  __syncthreads();
  if (t==0){
    float S=(rs[0]+rs[1])+(rs[2]+rs[3]);
    float C=(rc[0]+rc[1])+(rc[2]+rc[3]);
    out[0] = (C>0.0f) ? S/fmaxf(C,1.0f) : 0.0f;
  }
}

extern "C" void kernel_launch(void* const* d_in, const int* in_sizes, int n_in,
                              void* d_out, int out_size, void* d_ws, size_t ws_size,
                              hipStream_t stream) {
  const float* E      = (const float*)d_in[0];   // 4096x256 fp32
  const int*   labels = (const int*)d_in[1];     // 4096 int32
  float* out = (float*)d_out;

  float* sqw      = (float*)d_ws;          // 4096 f
  float* apw      = sqw + BN;              // 4096 f
  int*   hpw      = (int*)(apw + BN);      // 4096 i
  int*   anypw    = hpw + BN;              // 4096 i
  float* partials = (float*)(anypw + BN);  // up to 1024 f (ends at 67.6 KB)
  float* ET       = (float*)((char*)d_ws + 131072);  // 4 MB, 128 KB-aligned
  bool big = ws_size >= (size_t)(131072 + 4*1024*1024);

  k_sq  <<<BN/256, 256, 0, stream>>>(E, sqw);
  k_pos <<<256,    256, 0, stream>>>(E, labels, sqw, apw, hpw, anypw);
  if (big){
    k_tr    <<<256,   256, 0, stream>>>(E, ET);
    k_main_t<<<BN/MT, 512, 0, stream>>>(E, ET, labels, sqw, apw, hpw, anypw, partials);
    k_fin   <<<1,     256, 0, stream>>>(partials, out, BN/MT);
  } else {
    k_main  <<<BN/MI, 256, 0, stream>>>(E, labels, sqw, apw, hpw, anypw, partials);
    k_fin   <<<1,     256, 0, stream>>>(partials, out, BN/MI);
  }
}